// Round 9
// baseline (266.779 us; speedup 1.0000x reference)
//
#include <hip/hip_runtime.h>
#include <math.h>

// DigitCaps routing, FP32 in/out (proven r2/r6/r7). Round 9: single-launch.
//   P [256][9216] f32, W [1152][10][16][8] f32, out v [256][10][16] f32.
// All math identical to round 8 (PASS, absmax 1.95e-3) except:
//  - reduce_bc fused into tgemm waves (G stays in registers)
//  - b_log carried in registers (same wave owns same r each iteration)
//  - one kernel, 5 internal grid barriers (launch overhead was ~100 us of 200).

typedef __bf16 bf16x8 __attribute__((ext_vector_type(8)));
typedef float v4f __attribute__((ext_vector_type(4)));

#define NBLK 160

__device__ __forceinline__ float b2f(unsigned short u) {
    return __uint_as_float(((unsigned)u) << 16);
}
__device__ __forceinline__ unsigned short f2b(float f) {   // RNE, finite only
    unsigned x = __float_as_uint(f);
    return (unsigned short)((x + 0x7FFFu + ((x >> 16) & 1u)) >> 16);
}
__device__ __forceinline__ void split4(float4 x, unsigned short* h, unsigned short* l) {
    const float* xf = (const float*)&x;
    #pragma unroll
    for (int i = 0; i < 4; ++i) {
        h[i] = f2b(xf[i]);
        l[i] = f2b(xf[i] - b2f(h[i]));
    }
}
__device__ __forceinline__ uint2 pack4(const unsigned short* s) {
    uint2 w;
    w.x = s[0] | ((unsigned)s[1] << 16);
    w.y = s[2] | ((unsigned)s[3] << 16);
    return w;
}

// grid barrier: counter@bar[0], generation@bar[1]; agent scope acq/rel gives
// cross-XCD visibility (release flushes local L2, acquire invalidates).
__device__ void gbar(unsigned* bar) {
    __syncthreads();
    if (threadIdx.x == 0) {
        unsigned* cnt = bar;
        unsigned* gen = bar + 1;
        unsigned g = __hip_atomic_load(gen, __ATOMIC_RELAXED, __HIP_MEMORY_SCOPE_AGENT);
        unsigned a = __hip_atomic_fetch_add(cnt, 1u, __ATOMIC_ACQ_REL, __HIP_MEMORY_SCOPE_AGENT);
        if (a == NBLK - 1) {
            __hip_atomic_store(cnt, 0u, __ATOMIC_RELAXED, __HIP_MEMORY_SCOPE_AGENT);
            __hip_atomic_store(gen, g + 1u, __ATOMIC_RELEASE, __HIP_MEMORY_SCOPE_AGENT);
        } else {
            while (__hip_atomic_load(gen, __ATOMIC_ACQUIRE, __HIP_MEMORY_SCOPE_AGENT) == g)
                __builtin_amdgcn_s_sleep(1);
        }
    }
    __syncthreads();
}

// ---- sgemm + squash (round-8 proven, verbatim maps). 512 thr, 8-way split-K.
__device__ void sgemm_phase(
    const uint4* __restrict__ Ah, const uint4* __restrict__ Al,
    const uint4* __restrict__ Bh, const uint4* __restrict__ Bl,
    uint2* __restrict__ vth, uint2* __restrict__ vtl,
    float* __restrict__ outb, int uniform, int last, float* comb)
{
    const int tid = threadIdx.x;
    const int wave = tid >> 6, lane = tid & 63;
    const int lm = lane & 15, q = lane >> 4;
    const int c = blockIdx.x / 16, b0 = (blockIdx.x % 16) * 16;

    const uint4* Ahp = Ah + (size_t)(b0 + lm) * 1152 + q;
    const uint4* Alp = Al + (size_t)(b0 + lm) * 1152 + q;
    const uint4* Bhp = Bh + ((size_t)q * 10 + c) * 16 + lm;
    const uint4* Blp = Bl + ((size_t)q * 10 + c) * 16 + lm;

    v4f acc = {0.f, 0.f, 0.f, 0.f};
    const int kk0 = wave * 36;
    for (int kk = kk0; kk < kk0 + 36; ++kk) {
        bf16x8 ah = __builtin_bit_cast(bf16x8, Ahp[(size_t)kk * 4]);
        bf16x8 al = __builtin_bit_cast(bf16x8, Alp[(size_t)kk * 4]);
        bf16x8 bh = __builtin_bit_cast(bf16x8, Bhp[(size_t)kk * 640]);
        bf16x8 bl = __builtin_bit_cast(bf16x8, Blp[(size_t)kk * 640]);
        acc = __builtin_amdgcn_mfma_f32_16x16x32_bf16(ah, bh, acc, 0, 0, 0);
        acc = __builtin_amdgcn_mfma_f32_16x16x32_bf16(ah, bl, acc, 0, 0, 0);
        acc = __builtin_amdgcn_mfma_f32_16x16x32_bf16(al, bh, acc, 0, 0, 0);
    }
    #pragma unroll
    for (int r = 0; r < 4; ++r) comb[(wave * 64 + lane) * 4 + r] = acc[r];
    __syncthreads();
    if (wave == 0) {
        float s[4], sq[4];
        #pragma unroll
        for (int r = 0; r < 4; ++r) {
            s[r] = 0.f;
            #pragma unroll
            for (int w = 0; w < 8; ++w) s[r] += comb[(w * 64 + lane) * 4 + r];
            if (uniform) s[r] *= 0.1f;
            sq[r] = s[r] * s[r];
        }
        #pragma unroll
        for (int m = 1; m < 16; m <<= 1) {
            #pragma unroll
            for (int r = 0; r < 4; ++r) sq[r] += __shfl_xor(sq[r], m);
        }
        float v[4];
        #pragma unroll
        for (int r = 0; r < 4; ++r) {
            const float n = sq[r];
            v[r] = s[r] * sqrtf(n) / (1.0f + n);
        }
        if (!last) {
            unsigned short h[4], l[4];
            #pragma unroll
            for (int r = 0; r < 4; ++r) {
                h[r] = f2b(v[r]);
                l[r] = f2b(v[r] - b2f(h[r]));
            }
            const int o = (c * 16 + lm) * 64 + (b0 >> 2) + q;   // uint2 units
            vth[o] = pack4(h);
            vtl[o] = pack4(l);
        } else {
            #pragma unroll
            for (int r = 0; r < 4; ++r)
                outb[((b0 + q * 4 + r) * 10 + c) * 16 + lm] = v[r];
        }
    }
}

// ---- tgemm + fused reduce/logits/softmax/Bc. Wave owns tile t = wave*160+bx
// (t<576): ri = t*16..+15 i.e. r in {2t, 2t+1}. acc[c][rr] = G[c*16+q*4+rr][t*16+lm].
__device__ void tr_phase(
    const uint4* __restrict__ vth, const uint4* __restrict__ vtl,
    const uint4* __restrict__ Pth, const uint4* __restrict__ Ptl,
    const float* __restrict__ Wf, const float4* __restrict__ W4,
    unsigned short* __restrict__ Bh, unsigned short* __restrict__ Bl,
    float* blog)
{
    const int tid = threadIdx.x;
    const int wave = tid >> 6, lane = tid & 63;
    const int lm = lane & 15, q = lane >> 4;
    const int t = wave * NBLK + blockIdx.x;
    if (t >= 576) return;                 // idle waves fall through to gbar
    const int n0 = t * 16;

    v4f acc[10];
    #pragma unroll
    for (int mt = 0; mt < 10; ++mt) acc[mt] = (v4f){0.f, 0.f, 0.f, 0.f};
    #pragma unroll
    for (int kk = 0; kk < 8; ++kk) {
        bf16x8 ph = __builtin_bit_cast(bf16x8, Pth[(size_t)(n0 + lm) * 32 + kk * 4 + q]);
        bf16x8 pl = __builtin_bit_cast(bf16x8, Ptl[(size_t)(n0 + lm) * 32 + kk * 4 + q]);
        #pragma unroll
        for (int mt = 0; mt < 10; ++mt) {
            bf16x8 vh = __builtin_bit_cast(bf16x8, vth[(size_t)(mt * 16 + lm) * 32 + kk * 4 + q]);
            bf16x8 vl = __builtin_bit_cast(bf16x8, vtl[(size_t)(mt * 16 + lm) * 32 + kk * 4 + q]);
            acc[mt] = __builtin_amdgcn_mfma_f32_16x16x32_bf16(vh, ph, acc[mt], 0, 0, 0);
            acc[mt] = __builtin_amdgcn_mfma_f32_16x16x32_bf16(vh, pl, acc[mt], 0, 0, 0);
            acc[mt] = __builtin_amdgcn_mfma_f32_16x16x32_bf16(vl, ph, acc[mt], 0, 0, 0);
        }
    }
    // fused reduce: a[r,c] = (1/256) sum_{d,i} W[r,c,d,i] * G[c*16+d][r*8+i]
    const int r = (n0 >> 3) + (lm >> 3);  // lanes lm<8 -> r even, lm>=8 -> r+1
    const int i = lm & 7;
    float a[10];
    #pragma unroll
    for (int c = 0; c < 10; ++c) {
        const float* wr = Wf + ((size_t)r * 10 + c) * 128 + i;
        float p = 0.f;
        #pragma unroll
        for (int rr = 0; rr < 4; ++rr)
            p = fmaf(wr[(q * 4 + rr) * 8], acc[c][rr], p);   // d = q*4+rr
        a[c] = p;
    }
    // sum over q (masks 16,32) then over i (masks 1,2,4); bit3 (r-half) kept
    const int masks[5] = {16, 32, 1, 2, 4};
    #pragma unroll
    for (int m = 0; m < 5; ++m) {
        #pragma unroll
        for (int c = 0; c < 10; ++c) a[c] += __shfl_xor(a[c], masks[m]);
    }
    // per-lane logits for own r (register-resident across iterations) + softmax
    float mx = -1e30f;
    #pragma unroll
    for (int c = 0; c < 10; ++c) {
        blog[c] += a[c] * (1.0f / 256.0f);
        mx = fmaxf(mx, blog[c]);
    }
    float cl[10], den = 0.f;
    #pragma unroll
    for (int c = 0; c < 10; ++c) { cl[c] = __expf(blog[c] - mx); den += cl[c]; }
    const float inv = 1.0f / den;
    // Bc = cl[c]*W (hi/lo), 32 lanes per r, 4 consecutive elems per (lane,c)
    const int li = i * 4 + q;             // [0,32)
    #pragma unroll
    for (int c = 0; c < 10; ++c) {
        float4 w = W4[((size_t)r * 10 + c) * 32 + li];
        const float cs = cl[c] * inv;
        float xf[4] = {cs * w.x, cs * w.y, cs * w.z, cs * w.w};
        unsigned short h[4], l[4];
        #pragma unroll
        for (int k = 0; k < 4; ++k) {
            h[k] = f2b(xf[k]);
            l[k] = f2b(xf[k] - b2f(h[k]));
        }
        *(uint2*)&Bh[((size_t)r * 10 + c) * 128 + li * 4] = pack4(h);
        *(uint2*)&Bl[((size_t)r * 10 + c) * 128 + li * 4] = pack4(l);
    }
}

__global__ __launch_bounds__(512, 2) void mega_kernel(
    const float4* __restrict__ P4, const float4* __restrict__ W4,
    uint2* __restrict__ Ph, uint2* __restrict__ Pl,
    uint4* __restrict__ Pth, uint4* __restrict__ Ptl,
    uint2* __restrict__ Wh, uint2* __restrict__ Wl,
    unsigned short* __restrict__ Bh, unsigned short* __restrict__ Bl,
    uint2* __restrict__ vth, uint2* __restrict__ vtl,
    float* __restrict__ outb, unsigned* __restrict__ bar)
{
    __shared__ union {
        unsigned short sp[2][2][64 * 72];   // [halfblock][H/L] 36864 B
        float comb[8 * 64 * 4];             // 8192 B
    } sh;
    const int tid = threadIdx.x;
    const int bx = blockIdx.x;

    // ---- phase 0a: W hi/lo split (grid-stride) ----
    for (int idx = bx * 512 + tid; idx < 368640; idx += NBLK * 512) {
        unsigned short h[4], l[4];
        split4(W4[idx], h, l);
        Wh[idx] = pack4(h);
        Wl[idx] = pack4(l);
    }
    // ---- phase 0b: P hi/lo split + transpose (round-8 proven tile maps) ----
    {
        const int half = tid >> 8, t2 = tid & 255;
        unsigned short* ldsH = sh.sp[half][0];
        unsigned short* ldsL = sh.sp[half][1];
        const int hb = bx * 2 + half;       // 0..319
        for (int t = hb; t < 640; t += 320) {   // uniform 2 iterations
            const bool act = t < 576;
            const int b0 = (t & 3) * 64, k0 = (t >> 2) * 64;
            if (act) {
                #pragma unroll
                for (int j = 0; j < 4; ++j) {
                    int idx = t2 + j * 256;
                    int row = idx >> 4, col4 = idx & 15;
                    int g = (b0 + row) * 2304 + (k0 >> 2) + col4;
                    unsigned short h[4], l[4];
                    split4(P4[g], h, l);
                    Ph[g] = pack4(h);
                    Pl[g] = pack4(l);
                    #pragma unroll
                    for (int i2 = 0; i2 < 4; ++i2) {
                        ldsH[(col4 * 4 + i2) * 72 + row] = h[i2];
                        ldsL[(col4 * 4 + i2) * 72 + row] = l[i2];
                    }
                }
            }
            __syncthreads();
            if (act) {
                #pragma unroll
                for (int j = 0; j < 2; ++j) {
                    int idx = t2 + j * 256;
                    int krow = idx >> 3, bcol = idx & 7;
                    unsigned short h[8], l[8];
                    #pragma unroll
                    for (int i2 = 0; i2 < 8; ++i2) {
                        h[i2] = ldsH[krow * 72 + bcol * 8 + i2];
                        l[i2] = ldsL[krow * 72 + bcol * 8 + i2];
                    }
                    uint4 wh, wl;
                    wh.x = h[0] | ((unsigned)h[1] << 16); wh.y = h[2] | ((unsigned)h[3] << 16);
                    wh.z = h[4] | ((unsigned)h[5] << 16); wh.w = h[6] | ((unsigned)h[7] << 16);
                    wl.x = l[0] | ((unsigned)l[1] << 16); wl.y = l[2] | ((unsigned)l[3] << 16);
                    wl.z = l[4] | ((unsigned)l[5] << 16); wl.w = l[6] | ((unsigned)l[7] << 16);
                    Pth[(size_t)(k0 + krow) * 32 + (b0 >> 3) + bcol] = wh;
                    Ptl[(size_t)(k0 + krow) * 32 + (b0 >> 3) + bcol] = wl;
                }
            }
            __syncthreads();
        }
    }
    gbar(bar);

    float blog[10];
    #pragma unroll
    for (int c = 0; c < 10; ++c) blog[c] = 0.f;
    const float* Wf = (const float*)W4;

    // iter 0 (uniform c=0.1 post-MFMA)
    sgemm_phase((const uint4*)Ph, (const uint4*)Pl, (const uint4*)Wh, (const uint4*)Wl,
                vth, vtl, outb, 1, 0, sh.comb);
    gbar(bar);
    tr_phase((const uint4*)vth, (const uint4*)vtl, Pth, Ptl, Wf, W4, Bh, Bl, blog);
    gbar(bar);
    // iter 1
    sgemm_phase((const uint4*)Ph, (const uint4*)Pl, (const uint4*)Bh, (const uint4*)Bl,
                vth, vtl, outb, 0, 0, sh.comb);
    gbar(bar);
    tr_phase((const uint4*)vth, (const uint4*)vtl, Pth, Ptl, Wf, W4, Bh, Bl, blog);
    gbar(bar);
    // iter 2 -> out
    sgemm_phase((const uint4*)Ph, (const uint4*)Pl, (const uint4*)Bh, (const uint4*)Bl,
                vth, vtl, outb, 0, 1, sh.comb);
}

extern "C" void kernel_launch(void* const* d_in, const int* in_sizes, int n_in,
                              void* d_out, int out_size, void* d_ws, size_t ws_size,
                              hipStream_t stream)
{
    const float4* P4 = (const float4*)d_in[0];
    const float4* W4 = (const float4*)d_in[1];
    char* wsb = (char*)d_ws;
    // byte offsets (all 16B-aligned; sizes audited: Ph/Pl/Pth/Ptl 4718592 B,
    // Wh/Wl/Bh/Bl 2949120 B, vth/vtl 81920 B; total ~36.7 MB of ~268 MB)
    uint2* vth = (uint2*)(wsb + 131072);
    uint2* vtl = (uint2*)(wsb + 262144);
    uint2* Ph  = (uint2*)(wsb + 393216);
    uint2* Pl  = (uint2*)(wsb + 5242880);
    uint4* Pth = (uint4*)(wsb + 10485760);
    uint4* Ptl = (uint4*)(wsb + 15728640);
    uint2* Wh  = (uint2*)(wsb + 20971520);
    uint2* Wl  = (uint2*)(wsb + 25165824);
    unsigned short* Bh = (unsigned short*)(wsb + 29360128);
    unsigned short* Bl = (unsigned short*)(wsb + 33554432);
    unsigned* bar = (unsigned*)(wsb + 36700160);
    float* outb = (float*)d_out;

    hipMemsetAsync(bar, 0, 16, stream);   // zero barrier counter+generation
    mega_kernel<<<NBLK, 512, 0, stream>>>(P4, W4, Ph, Pl, Pth, Ptl, Wh, Wl,
                                          Bh, Bl, vth, vtl, outb, bar);
}

// Round 11
// 250.813 us; speedup vs baseline: 1.0637x; 1.0637x over previous
//
#include <hip/hip_runtime.h>
#include <math.h>

// DigitCaps routing, FP32 in/out (proven r2/r6/r7). Single-launch (r9 PASS).
//   P [256][9216] f32, W [1152][10][16][8] f32, out v [256][10][16] f32.
// Round 11: gbar fix, compiling spelling. r9's spin polled ACQUIRE@AGENT ->
// buffer_inv per poll -> continuous L2 invalidation (FETCH 107MB, body 217us,
// all pipes idle). Now: RELAXED polls + ONE acquire load on exit + s_sleep(16).

typedef __bf16 bf16x8 __attribute__((ext_vector_type(8)));
typedef float v4f __attribute__((ext_vector_type(4)));

#define NBLK 160

__device__ __forceinline__ float b2f(unsigned short u) {
    return __uint_as_float(((unsigned)u) << 16);
}
__device__ __forceinline__ unsigned short f2b(float f) {   // RNE, finite only
    unsigned x = __float_as_uint(f);
    return (unsigned short)((x + 0x7FFFu + ((x >> 16) & 1u)) >> 16);
}
__device__ __forceinline__ void split4(float4 x, unsigned short* h, unsigned short* l) {
    const float* xf = (const float*)&x;
    #pragma unroll
    for (int i = 0; i < 4; ++i) {
        h[i] = f2b(xf[i]);
        l[i] = f2b(xf[i] - b2f(h[i]));
    }
}
__device__ __forceinline__ uint2 pack4(const unsigned short* s) {
    uint2 w;
    w.x = s[0] | ((unsigned)s[1] << 16);
    w.y = s[2] | ((unsigned)s[3] << 16);
    return w;
}

// grid barrier: counter@bar[0], generation@bar[1].
// Arrive: ACQ_REL fetch_add (release = local L2 writeback).
// Wait: RELAXED polls (no cache maintenance per poll), then ONE acquire load
// of gen (reads the released value -> synchronizes-with -> single buffer_inv).
__device__ void gbar(unsigned* bar) {
    __syncthreads();
    if (threadIdx.x == 0) {
        unsigned* cnt = bar;
        unsigned* gen = bar + 1;
        unsigned g = __hip_atomic_load(gen, __ATOMIC_RELAXED, __HIP_MEMORY_SCOPE_AGENT);
        unsigned a = __hip_atomic_fetch_add(cnt, 1u, __ATOMIC_ACQ_REL, __HIP_MEMORY_SCOPE_AGENT);
        if (a == NBLK - 1) {
            __hip_atomic_store(cnt, 0u, __ATOMIC_RELAXED, __HIP_MEMORY_SCOPE_AGENT);
            __hip_atomic_store(gen, g + 1u, __ATOMIC_RELEASE, __HIP_MEMORY_SCOPE_AGENT);
        } else {
            while (__hip_atomic_load(gen, __ATOMIC_RELAXED, __HIP_MEMORY_SCOPE_AGENT) == g)
                __builtin_amdgcn_s_sleep(16);
            (void)__hip_atomic_load(gen, __ATOMIC_ACQUIRE, __HIP_MEMORY_SCOPE_AGENT);
        }
    }
    __syncthreads();
}

// ---- sgemm + squash (round-8/9 proven, verbatim). 512 thr, 8-way split-K.
__device__ void sgemm_phase(
    const uint4* __restrict__ Ah, const uint4* __restrict__ Al,
    const uint4* __restrict__ Bh, const uint4* __restrict__ Bl,
    uint2* __restrict__ vth, uint2* __restrict__ vtl,
    float* __restrict__ outb, int uniform, int last, float* comb)
{
    const int tid = threadIdx.x;
    const int wave = tid >> 6, lane = tid & 63;
    const int lm = lane & 15, q = lane >> 4;
    const int c = blockIdx.x / 16, b0 = (blockIdx.x % 16) * 16;

    const uint4* Ahp = Ah + (size_t)(b0 + lm) * 1152 + q;
    const uint4* Alp = Al + (size_t)(b0 + lm) * 1152 + q;
    const uint4* Bhp = Bh + ((size_t)q * 10 + c) * 16 + lm;
    const uint4* Blp = Bl + ((size_t)q * 10 + c) * 16 + lm;

    v4f acc = {0.f, 0.f, 0.f, 0.f};
    const int kk0 = wave * 36;
    for (int kk = kk0; kk < kk0 + 36; ++kk) {
        bf16x8 ah = __builtin_bit_cast(bf16x8, Ahp[(size_t)kk * 4]);
        bf16x8 al = __builtin_bit_cast(bf16x8, Alp[(size_t)kk * 4]);
        bf16x8 bh = __builtin_bit_cast(bf16x8, Bhp[(size_t)kk * 640]);
        bf16x8 bl = __builtin_bit_cast(bf16x8, Blp[(size_t)kk * 640]);
        acc = __builtin_amdgcn_mfma_f32_16x16x32_bf16(ah, bh, acc, 0, 0, 0);
        acc = __builtin_amdgcn_mfma_f32_16x16x32_bf16(ah, bl, acc, 0, 0, 0);
        acc = __builtin_amdgcn_mfma_f32_16x16x32_bf16(al, bh, acc, 0, 0, 0);
    }
    #pragma unroll
    for (int r = 0; r < 4; ++r) comb[(wave * 64 + lane) * 4 + r] = acc[r];
    __syncthreads();
    if (wave == 0) {
        float s[4], sq[4];
        #pragma unroll
        for (int r = 0; r < 4; ++r) {
            s[r] = 0.f;
            #pragma unroll
            for (int w = 0; w < 8; ++w) s[r] += comb[(w * 64 + lane) * 4 + r];
            if (uniform) s[r] *= 0.1f;
            sq[r] = s[r] * s[r];
        }
        #pragma unroll
        for (int m = 1; m < 16; m <<= 1) {
            #pragma unroll
            for (int r = 0; r < 4; ++r) sq[r] += __shfl_xor(sq[r], m);
        }
        float v[4];
        #pragma unroll
        for (int r = 0; r < 4; ++r) {
            const float n = sq[r];
            v[r] = s[r] * sqrtf(n) / (1.0f + n);
        }
        if (!last) {
            unsigned short h[4], l[4];
            #pragma unroll
            for (int r = 0; r < 4; ++r) {
                h[r] = f2b(v[r]);
                l[r] = f2b(v[r] - b2f(h[r]));
            }
            const int o = (c * 16 + lm) * 64 + (b0 >> 2) + q;   // uint2 units
            vth[o] = pack4(h);
            vtl[o] = pack4(l);
        } else {
            #pragma unroll
            for (int r = 0; r < 4; ++r)
                outb[((b0 + q * 4 + r) * 10 + c) * 16 + lm] = v[r];
        }
    }
}

// ---- tgemm + fused reduce/logits/softmax/Bc (round-9 proven, verbatim).
__device__ void tr_phase(
    const uint4* __restrict__ vth, const uint4* __restrict__ vtl,
    const uint4* __restrict__ Pth, const uint4* __restrict__ Ptl,
    const float* __restrict__ Wf, const float4* __restrict__ W4,
    unsigned short* __restrict__ Bh, unsigned short* __restrict__ Bl,
    float* blog)
{
    const int tid = threadIdx.x;
    const int wave = tid >> 6, lane = tid & 63;
    const int lm = lane & 15, q = lane >> 4;
    const int t = wave * NBLK + blockIdx.x;
    if (t >= 576) return;
    const int n0 = t * 16;

    v4f acc[10];
    #pragma unroll
    for (int mt = 0; mt < 10; ++mt) acc[mt] = (v4f){0.f, 0.f, 0.f, 0.f};
    #pragma unroll
    for (int kk = 0; kk < 8; ++kk) {
        bf16x8 ph = __builtin_bit_cast(bf16x8, Pth[(size_t)(n0 + lm) * 32 + kk * 4 + q]);
        bf16x8 pl = __builtin_bit_cast(bf16x8, Ptl[(size_t)(n0 + lm) * 32 + kk * 4 + q]);
        #pragma unroll
        for (int mt = 0; mt < 10; ++mt) {
            bf16x8 vh = __builtin_bit_cast(bf16x8, vth[(size_t)(mt * 16 + lm) * 32 + kk * 4 + q]);
            bf16x8 vl = __builtin_bit_cast(bf16x8, vtl[(size_t)(mt * 16 + lm) * 32 + kk * 4 + q]);
            acc[mt] = __builtin_amdgcn_mfma_f32_16x16x32_bf16(vh, ph, acc[mt], 0, 0, 0);
            acc[mt] = __builtin_amdgcn_mfma_f32_16x16x32_bf16(vh, pl, acc[mt], 0, 0, 0);
            acc[mt] = __builtin_amdgcn_mfma_f32_16x16x32_bf16(vl, ph, acc[mt], 0, 0, 0);
        }
    }
    const int r = (n0 >> 3) + (lm >> 3);
    const int i = lm & 7;
    float a[10];
    #pragma unroll
    for (int c = 0; c < 10; ++c) {
        const float* wr = Wf + ((size_t)r * 10 + c) * 128 + i;
        float p = 0.f;
        #pragma unroll
        for (int rr = 0; rr < 4; ++rr)
            p = fmaf(wr[(q * 4 + rr) * 8], acc[c][rr], p);   // d = q*4+rr
        a[c] = p;
    }
    const int masks[5] = {16, 32, 1, 2, 4};
    #pragma unroll
    for (int m = 0; m < 5; ++m) {
        #pragma unroll
        for (int c = 0; c < 10; ++c) a[c] += __shfl_xor(a[c], masks[m]);
    }
    float mx = -1e30f;
    #pragma unroll
    for (int c = 0; c < 10; ++c) {
        blog[c] += a[c] * (1.0f / 256.0f);
        mx = fmaxf(mx, blog[c]);
    }
    float cl[10], den = 0.f;
    #pragma unroll
    for (int c = 0; c < 10; ++c) { cl[c] = __expf(blog[c] - mx); den += cl[c]; }
    const float inv = 1.0f / den;
    const int li = i * 4 + q;
    #pragma unroll
    for (int c = 0; c < 10; ++c) {
        float4 w = W4[((size_t)r * 10 + c) * 32 + li];
        const float cs = cl[c] * inv;
        float xf[4] = {cs * w.x, cs * w.y, cs * w.z, cs * w.w};
        unsigned short h[4], l[4];
        #pragma unroll
        for (int k = 0; k < 4; ++k) {
            h[k] = f2b(xf[k]);
            l[k] = f2b(xf[k] - b2f(h[k]));
        }
        *(uint2*)&Bh[((size_t)r * 10 + c) * 128 + li * 4] = pack4(h);
        *(uint2*)&Bl[((size_t)r * 10 + c) * 128 + li * 4] = pack4(l);
    }
}

__global__ __launch_bounds__(512, 2) void mega_kernel(
    const float4* __restrict__ P4, const float4* __restrict__ W4,
    uint2* __restrict__ Ph, uint2* __restrict__ Pl,
    uint4* __restrict__ Pth, uint4* __restrict__ Ptl,
    uint2* __restrict__ Wh, uint2* __restrict__ Wl,
    unsigned short* __restrict__ Bh, unsigned short* __restrict__ Bl,
    uint2* __restrict__ vth, uint2* __restrict__ vtl,
    float* __restrict__ outb, unsigned* __restrict__ bar)
{
    __shared__ union {
        unsigned short sp[2][2][64 * 72];   // [halfblock][H/L] 36864 B
        float comb[8 * 64 * 4];             // 8192 B
    } sh;
    const int tid = threadIdx.x;
    const int bx = blockIdx.x;

    // ---- phase 0a: W hi/lo split (grid-stride) ----
    for (int idx = bx * 512 + tid; idx < 368640; idx += NBLK * 512) {
        unsigned short h[4], l[4];
        split4(W4[idx], h, l);
        Wh[idx] = pack4(h);
        Wl[idx] = pack4(l);
    }
    // ---- phase 0b: P hi/lo split + transpose ----
    {
        const int half = tid >> 8, t2 = tid & 255;
        unsigned short* ldsH = sh.sp[half][0];
        unsigned short* ldsL = sh.sp[half][1];
        const int hb = bx * 2 + half;       // 0..319
        for (int t = hb; t < 640; t += 320) {
            const bool act = t < 576;
            const int b0 = (t & 3) * 64, k0 = (t >> 2) * 64;
            if (act) {
                #pragma unroll
                for (int j = 0; j < 4; ++j) {
                    int idx = t2 + j * 256;
                    int row = idx >> 4, col4 = idx & 15;
                    int g = (b0 + row) * 2304 + (k0 >> 2) + col4;
                    unsigned short h[4], l[4];
                    split4(P4[g], h, l);
                    Ph[g] = pack4(h);
                    Pl[g] = pack4(l);
                    #pragma unroll
                    for (int i2 = 0; i2 < 4; ++i2) {
                        ldsH[(col4 * 4 + i2) * 72 + row] = h[i2];
                        ldsL[(col4 * 4 + i2) * 72 + row] = l[i2];
                    }
                }
            }
            __syncthreads();
            if (act) {
                #pragma unroll
                for (int j = 0; j < 2; ++j) {
                    int idx = t2 + j * 256;
                    int krow = idx >> 3, bcol = idx & 7;
                    unsigned short h[8], l[8];
                    #pragma unroll
                    for (int i2 = 0; i2 < 8; ++i2) {
                        h[i2] = ldsH[krow * 72 + bcol * 8 + i2];
                        l[i2] = ldsL[krow * 72 + bcol * 8 + i2];
                    }
                    uint4 wh, wl;
                    wh.x = h[0] | ((unsigned)h[1] << 16); wh.y = h[2] | ((unsigned)h[3] << 16);
                    wh.z = h[4] | ((unsigned)h[5] << 16); wh.w = h[6] | ((unsigned)h[7] << 16);
                    wl.x = l[0] | ((unsigned)l[1] << 16); wl.y = l[2] | ((unsigned)l[3] << 16);
                    wl.z = l[4] | ((unsigned)l[5] << 16); wl.w = l[6] | ((unsigned)l[7] << 16);
                    Pth[(size_t)(k0 + krow) * 32 + (b0 >> 3) + bcol] = wh;
                    Ptl[(size_t)(k0 + krow) * 32 + (b0 >> 3) + bcol] = wl;
                }
            }
            __syncthreads();
        }
    }
    gbar(bar);

    float blog[10];
    #pragma unroll
    for (int c = 0; c < 10; ++c) blog[c] = 0.f;
    const float* Wf = (const float*)W4;

    // iter 0 (uniform c=0.1 post-MFMA)
    sgemm_phase((const uint4*)Ph, (const uint4*)Pl, (const uint4*)Wh, (const uint4*)Wl,
                vth, vtl, outb, 1, 0, sh.comb);
    gbar(bar);
    tr_phase((const uint4*)vth, (const uint4*)vtl, Pth, Ptl, Wf, W4, Bh, Bl, blog);
    gbar(bar);
    // iter 1
    sgemm_phase((const uint4*)Ph, (const uint4*)Pl, (const uint4*)Bh, (const uint4*)Bl,
                vth, vtl, outb, 0, 0, sh.comb);
    gbar(bar);
    tr_phase((const uint4*)vth, (const uint4*)vtl, Pth, Ptl, Wf, W4, Bh, Bl, blog);
    gbar(bar);
    // iter 2 -> out
    sgemm_phase((const uint4*)Ph, (const uint4*)Pl, (const uint4*)Bh, (const uint4*)Bl,
                vth, vtl, outb, 0, 1, sh.comb);
}

extern "C" void kernel_launch(void* const* d_in, const int* in_sizes, int n_in,
                              void* d_out, int out_size, void* d_ws, size_t ws_size,
                              hipStream_t stream)
{
    const float4* P4 = (const float4*)d_in[0];
    const float4* W4 = (const float4*)d_in[1];
    char* wsb = (char*)d_ws;
    uint2* vth = (uint2*)(wsb + 131072);
    uint2* vtl = (uint2*)(wsb + 262144);
    uint2* Ph  = (uint2*)(wsb + 393216);
    uint2* Pl  = (uint2*)(wsb + 5242880);
    uint4* Pth = (uint4*)(wsb + 10485760);
    uint4* Ptl = (uint4*)(wsb + 15728640);
    uint2* Wh  = (uint2*)(wsb + 20971520);
    uint2* Wl  = (uint2*)(wsb + 25165824);
    unsigned short* Bh = (unsigned short*)(wsb + 29360128);
    unsigned short* Bl = (unsigned short*)(wsb + 33554432);
    unsigned* bar = (unsigned*)(wsb + 36700160);
    float* outb = (float*)d_out;

    (void)hipMemsetAsync(bar, 0, 16, stream);   // zero barrier counter+generation
    mega_kernel<<<NBLK, 512, 0, stream>>>(P4, W4, Ph, Pl, Pth, Ptl, Wh, Wl,
                                          Bh, Bl, vth, vtl, outb, bar);
}

// Round 12
// 221.649 us; speedup vs baseline: 1.2036x; 1.1316x over previous
//
#include <hip/hip_runtime.h>
#include <math.h>

// DigitCaps routing, FP32 in/out (proven r2/r6/r7). Single-launch (r9/r11 PASS).
//   P [256][9216] f32, W [1152][10][16][8] f32, out v [256][10][16] f32.
// Round 12: hierarchical grid barrier. r11 evidence: body 196us with all pipes
// idle = ~145us in 6 barriers = 960 serialized cross-XCD RMWs on ONE line.
// Fix: 8 sub-counters on separate 128B lines (20 arrivals each, parallel) ->
// root (8 arrivals) -> gen release. Phases byte-identical to r11.

typedef __bf16 bf16x8 __attribute__((ext_vector_type(8)));
typedef float v4f __attribute__((ext_vector_type(4)));

#define NBLK 160

__device__ __forceinline__ float b2f(unsigned short u) {
    return __uint_as_float(((unsigned)u) << 16);
}
__device__ __forceinline__ unsigned short f2b(float f) {   // RNE, finite only
    unsigned x = __float_as_uint(f);
    return (unsigned short)((x + 0x7FFFu + ((x >> 16) & 1u)) >> 16);
}
__device__ __forceinline__ void split4(float4 x, unsigned short* h, unsigned short* l) {
    const float* xf = (const float*)&x;
    #pragma unroll
    for (int i = 0; i < 4; ++i) {
        h[i] = f2b(xf[i]);
        l[i] = f2b(xf[i] - b2f(h[i]));
    }
}
__device__ __forceinline__ uint2 pack4(const unsigned short* s) {
    uint2 w;
    w.x = s[0] | ((unsigned)s[1] << 16);
    w.y = s[2] | ((unsigned)s[3] << 16);
    return w;
}

// Two-level grid barrier. Layout (uint units): sub[s]@32*s (s=0..7, 128B apart),
// root@288, gen@320. All RMWs ACQ_REL -> release-sequence transitivity:
// every block's writes happen-before the gen release store; waiters acquire it.
__device__ void gbar(unsigned* bar) {
    __syncthreads();
    if (threadIdx.x == 0) {
        unsigned* sub  = bar + 32 * (blockIdx.x & 7);
        unsigned* root = bar + 288;
        unsigned* gen  = bar + 320;
        unsigned g = __hip_atomic_load(gen, __ATOMIC_RELAXED, __HIP_MEMORY_SCOPE_AGENT);
        unsigned a = __hip_atomic_fetch_add(sub, 1u, __ATOMIC_ACQ_REL, __HIP_MEMORY_SCOPE_AGENT);
        if (a == (NBLK / 8) - 1) {
            __hip_atomic_store(sub, 0u, __ATOMIC_RELAXED, __HIP_MEMORY_SCOPE_AGENT);
            unsigned b = __hip_atomic_fetch_add(root, 1u, __ATOMIC_ACQ_REL, __HIP_MEMORY_SCOPE_AGENT);
            if (b == 7) {
                __hip_atomic_store(root, 0u, __ATOMIC_RELAXED, __HIP_MEMORY_SCOPE_AGENT);
                __hip_atomic_store(gen, g + 1u, __ATOMIC_RELEASE, __HIP_MEMORY_SCOPE_AGENT);
            }
        }
        while (__hip_atomic_load(gen, __ATOMIC_RELAXED, __HIP_MEMORY_SCOPE_AGENT) == g)
            __builtin_amdgcn_s_sleep(8);
        (void)__hip_atomic_load(gen, __ATOMIC_ACQUIRE, __HIP_MEMORY_SCOPE_AGENT);
    }
    __syncthreads();
}

// ---- sgemm + squash (r8/r9/r11 proven, verbatim). 512 thr, 8-way split-K.
__device__ void sgemm_phase(
    const uint4* __restrict__ Ah, const uint4* __restrict__ Al,
    const uint4* __restrict__ Bh, const uint4* __restrict__ Bl,
    uint2* __restrict__ vth, uint2* __restrict__ vtl,
    float* __restrict__ outb, int uniform, int last, float* comb)
{
    const int tid = threadIdx.x;
    const int wave = tid >> 6, lane = tid & 63;
    const int lm = lane & 15, q = lane >> 4;
    const int c = blockIdx.x / 16, b0 = (blockIdx.x % 16) * 16;

    const uint4* Ahp = Ah + (size_t)(b0 + lm) * 1152 + q;
    const uint4* Alp = Al + (size_t)(b0 + lm) * 1152 + q;
    const uint4* Bhp = Bh + ((size_t)q * 10 + c) * 16 + lm;
    const uint4* Blp = Bl + ((size_t)q * 10 + c) * 16 + lm;

    v4f acc = {0.f, 0.f, 0.f, 0.f};
    const int kk0 = wave * 36;
    for (int kk = kk0; kk < kk0 + 36; ++kk) {
        bf16x8 ah = __builtin_bit_cast(bf16x8, Ahp[(size_t)kk * 4]);
        bf16x8 al = __builtin_bit_cast(bf16x8, Alp[(size_t)kk * 4]);
        bf16x8 bh = __builtin_bit_cast(bf16x8, Bhp[(size_t)kk * 640]);
        bf16x8 bl = __builtin_bit_cast(bf16x8, Blp[(size_t)kk * 640]);
        acc = __builtin_amdgcn_mfma_f32_16x16x32_bf16(ah, bh, acc, 0, 0, 0);
        acc = __builtin_amdgcn_mfma_f32_16x16x32_bf16(ah, bl, acc, 0, 0, 0);
        acc = __builtin_amdgcn_mfma_f32_16x16x32_bf16(al, bh, acc, 0, 0, 0);
    }
    #pragma unroll
    for (int r = 0; r < 4; ++r) comb[(wave * 64 + lane) * 4 + r] = acc[r];
    __syncthreads();
    if (wave == 0) {
        float s[4], sq[4];
        #pragma unroll
        for (int r = 0; r < 4; ++r) {
            s[r] = 0.f;
            #pragma unroll
            for (int w = 0; w < 8; ++w) s[r] += comb[(w * 64 + lane) * 4 + r];
            if (uniform) s[r] *= 0.1f;
            sq[r] = s[r] * s[r];
        }
        #pragma unroll
        for (int m = 1; m < 16; m <<= 1) {
            #pragma unroll
            for (int r = 0; r < 4; ++r) sq[r] += __shfl_xor(sq[r], m);
        }
        float v[4];
        #pragma unroll
        for (int r = 0; r < 4; ++r) {
            const float n = sq[r];
            v[r] = s[r] * sqrtf(n) / (1.0f + n);
        }
        if (!last) {
            unsigned short h[4], l[4];
            #pragma unroll
            for (int r = 0; r < 4; ++r) {
                h[r] = f2b(v[r]);
                l[r] = f2b(v[r] - b2f(h[r]));
            }
            const int o = (c * 16 + lm) * 64 + (b0 >> 2) + q;   // uint2 units
            vth[o] = pack4(h);
            vtl[o] = pack4(l);
        } else {
            #pragma unroll
            for (int r = 0; r < 4; ++r)
                outb[((b0 + q * 4 + r) * 10 + c) * 16 + lm] = v[r];
        }
    }
}

// ---- tgemm + fused reduce/logits/softmax/Bc (r9/r11 proven, verbatim).
__device__ void tr_phase(
    const uint4* __restrict__ vth, const uint4* __restrict__ vtl,
    const uint4* __restrict__ Pth, const uint4* __restrict__ Ptl,
    const float* __restrict__ Wf, const float4* __restrict__ W4,
    unsigned short* __restrict__ Bh, unsigned short* __restrict__ Bl,
    float* blog)
{
    const int tid = threadIdx.x;
    const int wave = tid >> 6, lane = tid & 63;
    const int lm = lane & 15, q = lane >> 4;
    const int t = wave * NBLK + blockIdx.x;
    if (t >= 576) return;
    const int n0 = t * 16;

    v4f acc[10];
    #pragma unroll
    for (int mt = 0; mt < 10; ++mt) acc[mt] = (v4f){0.f, 0.f, 0.f, 0.f};
    #pragma unroll
    for (int kk = 0; kk < 8; ++kk) {
        bf16x8 ph = __builtin_bit_cast(bf16x8, Pth[(size_t)(n0 + lm) * 32 + kk * 4 + q]);
        bf16x8 pl = __builtin_bit_cast(bf16x8, Ptl[(size_t)(n0 + lm) * 32 + kk * 4 + q]);
        #pragma unroll
        for (int mt = 0; mt < 10; ++mt) {
            bf16x8 vh = __builtin_bit_cast(bf16x8, vth[(size_t)(mt * 16 + lm) * 32 + kk * 4 + q]);
            bf16x8 vl = __builtin_bit_cast(bf16x8, vtl[(size_t)(mt * 16 + lm) * 32 + kk * 4 + q]);
            acc[mt] = __builtin_amdgcn_mfma_f32_16x16x32_bf16(vh, ph, acc[mt], 0, 0, 0);
            acc[mt] = __builtin_amdgcn_mfma_f32_16x16x32_bf16(vh, pl, acc[mt], 0, 0, 0);
            acc[mt] = __builtin_amdgcn_mfma_f32_16x16x32_bf16(vl, ph, acc[mt], 0, 0, 0);
        }
    }
    const int r = (n0 >> 3) + (lm >> 3);
    const int i = lm & 7;
    float a[10];
    #pragma unroll
    for (int c = 0; c < 10; ++c) {
        const float* wr = Wf + ((size_t)r * 10 + c) * 128 + i;
        float p = 0.f;
        #pragma unroll
        for (int rr = 0; rr < 4; ++rr)
            p = fmaf(wr[(q * 4 + rr) * 8], acc[c][rr], p);   // d = q*4+rr
        a[c] = p;
    }
    const int masks[5] = {16, 32, 1, 2, 4};
    #pragma unroll
    for (int m = 0; m < 5; ++m) {
        #pragma unroll
        for (int c = 0; c < 10; ++c) a[c] += __shfl_xor(a[c], masks[m]);
    }
    float mx = -1e30f;
    #pragma unroll
    for (int c = 0; c < 10; ++c) {
        blog[c] += a[c] * (1.0f / 256.0f);
        mx = fmaxf(mx, blog[c]);
    }
    float cl[10], den = 0.f;
    #pragma unroll
    for (int c = 0; c < 10; ++c) { cl[c] = __expf(blog[c] - mx); den += cl[c]; }
    const float inv = 1.0f / den;
    const int li = i * 4 + q;
    #pragma unroll
    for (int c = 0; c < 10; ++c) {
        float4 w = W4[((size_t)r * 10 + c) * 32 + li];
        const float cs = cl[c] * inv;
        float xf[4] = {cs * w.x, cs * w.y, cs * w.z, cs * w.w};
        unsigned short h[4], l[4];
        #pragma unroll
        for (int k = 0; k < 4; ++k) {
            h[k] = f2b(xf[k]);
            l[k] = f2b(xf[k] - b2f(h[k]));
        }
        *(uint2*)&Bh[((size_t)r * 10 + c) * 128 + li * 4] = pack4(h);
        *(uint2*)&Bl[((size_t)r * 10 + c) * 128 + li * 4] = pack4(l);
    }
}

__global__ __launch_bounds__(512, 2) void mega_kernel(
    const float4* __restrict__ P4, const float4* __restrict__ W4,
    uint2* __restrict__ Ph, uint2* __restrict__ Pl,
    uint4* __restrict__ Pth, uint4* __restrict__ Ptl,
    uint2* __restrict__ Wh, uint2* __restrict__ Wl,
    unsigned short* __restrict__ Bh, unsigned short* __restrict__ Bl,
    uint2* __restrict__ vth, uint2* __restrict__ vtl,
    float* __restrict__ outb, unsigned* __restrict__ bar)
{
    __shared__ union {
        unsigned short sp[2][2][64 * 72];   // [halfblock][H/L] 36864 B
        float comb[8 * 64 * 4];             // 8192 B
    } sh;
    const int tid = threadIdx.x;
    const int bx = blockIdx.x;

    // ---- phase 0a: W hi/lo split (grid-stride) ----
    for (int idx = bx * 512 + tid; idx < 368640; idx += NBLK * 512) {
        unsigned short h[4], l[4];
        split4(W4[idx], h, l);
        Wh[idx] = pack4(h);
        Wl[idx] = pack4(l);
    }
    // ---- phase 0b: P hi/lo split + transpose ----
    {
        const int half = tid >> 8, t2 = tid & 255;
        unsigned short* ldsH = sh.sp[half][0];
        unsigned short* ldsL = sh.sp[half][1];
        const int hb = bx * 2 + half;       // 0..319
        for (int t = hb; t < 640; t += 320) {
            const bool act = t < 576;
            const int b0 = (t & 3) * 64, k0 = (t >> 2) * 64;
            if (act) {
                #pragma unroll
                for (int j = 0; j < 4; ++j) {
                    int idx = t2 + j * 256;
                    int row = idx >> 4, col4 = idx & 15;
                    int g = (b0 + row) * 2304 + (k0 >> 2) + col4;
                    unsigned short h[4], l[4];
                    split4(P4[g], h, l);
                    Ph[g] = pack4(h);
                    Pl[g] = pack4(l);
                    #pragma unroll
                    for (int i2 = 0; i2 < 4; ++i2) {
                        ldsH[(col4 * 4 + i2) * 72 + row] = h[i2];
                        ldsL[(col4 * 4 + i2) * 72 + row] = l[i2];
                    }
                }
            }
            __syncthreads();
            if (act) {
                #pragma unroll
                for (int j = 0; j < 2; ++j) {
                    int idx = t2 + j * 256;
                    int krow = idx >> 3, bcol = idx & 7;
                    unsigned short h[8], l[8];
                    #pragma unroll
                    for (int i2 = 0; i2 < 8; ++i2) {
                        h[i2] = ldsH[krow * 72 + bcol * 8 + i2];
                        l[i2] = ldsL[krow * 72 + bcol * 8 + i2];
                    }
                    uint4 wh, wl;
                    wh.x = h[0] | ((unsigned)h[1] << 16); wh.y = h[2] | ((unsigned)h[3] << 16);
                    wh.z = h[4] | ((unsigned)h[5] << 16); wh.w = h[6] | ((unsigned)h[7] << 16);
                    wl.x = l[0] | ((unsigned)l[1] << 16); wl.y = l[2] | ((unsigned)l[3] << 16);
                    wl.z = l[4] | ((unsigned)l[5] << 16); wl.w = l[6] | ((unsigned)l[7] << 16);
                    Pth[(size_t)(k0 + krow) * 32 + (b0 >> 3) + bcol] = wh;
                    Ptl[(size_t)(k0 + krow) * 32 + (b0 >> 3) + bcol] = wl;
                }
            }
            __syncthreads();
        }
    }
    gbar(bar);

    float blog[10];
    #pragma unroll
    for (int c = 0; c < 10; ++c) blog[c] = 0.f;
    const float* Wf = (const float*)W4;

    // iter 0 (uniform c=0.1 post-MFMA)
    sgemm_phase((const uint4*)Ph, (const uint4*)Pl, (const uint4*)Wh, (const uint4*)Wl,
                vth, vtl, outb, 1, 0, sh.comb);
    gbar(bar);
    tr_phase((const uint4*)vth, (const uint4*)vtl, Pth, Ptl, Wf, W4, Bh, Bl, blog);
    gbar(bar);
    // iter 1
    sgemm_phase((const uint4*)Ph, (const uint4*)Pl, (const uint4*)Bh, (const uint4*)Bl,
                vth, vtl, outb, 0, 0, sh.comb);
    gbar(bar);
    tr_phase((const uint4*)vth, (const uint4*)vtl, Pth, Ptl, Wf, W4, Bh, Bl, blog);
    gbar(bar);
    // iter 2 -> out
    sgemm_phase((const uint4*)Ph, (const uint4*)Pl, (const uint4*)Bh, (const uint4*)Bl,
                vth, vtl, outb, 0, 1, sh.comb);
}

extern "C" void kernel_launch(void* const* d_in, const int* in_sizes, int n_in,
                              void* d_out, int out_size, void* d_ws, size_t ws_size,
                              hipStream_t stream)
{
    const float4* P4 = (const float4*)d_in[0];
    const float4* W4 = (const float4*)d_in[1];
    char* wsb = (char*)d_ws;
    uint2* vth = (uint2*)(wsb + 131072);
    uint2* vtl = (uint2*)(wsb + 262144);
    uint2* Ph  = (uint2*)(wsb + 393216);
    uint2* Pl  = (uint2*)(wsb + 5242880);
    uint4* Pth = (uint4*)(wsb + 10485760);
    uint4* Ptl = (uint4*)(wsb + 15728640);
    uint2* Wh  = (uint2*)(wsb + 20971520);
    uint2* Wl  = (uint2*)(wsb + 25165824);
    unsigned short* Bh = (unsigned short*)(wsb + 29360128);
    unsigned short* Bl = (unsigned short*)(wsb + 33554432);
    unsigned* bar = (unsigned*)(wsb + 36700160);
    float* outb = (float*)d_out;

    (void)hipMemsetAsync(bar, 0, 2048, stream);  // zero sub/root/gen counters
    mega_kernel<<<NBLK, 512, 0, stream>>>(P4, W4, Ph, Pl, Pth, Ptl, Wh, Wl,
                                          Bh, Bl, vth, vtl, outb, bar);
}

// Round 13
// 205.401 us; speedup vs baseline: 1.2988x; 1.0791x over previous
//
#include <hip/hip_runtime.h>
#include <math.h>

// DigitCaps routing, FP32 in/out. Single-launch. Round 13: minimize barrier
// work. r12 evidence: 6 barriers x 160 release-wbl2 + full-L2 refetch each
// phase (FETCH pinned 107MB) dominate. Now: 4 barriers; tr emits c_coef
// (46KB) instead of Bc planes (5.9MB); sgemm scales+splits c*W in-register
// (same bytes as reading planes); split-P phase folded into phase A.

typedef __bf16 bf16x8 __attribute__((ext_vector_type(8)));
typedef float v4f __attribute__((ext_vector_type(4)));

#define NBLK 160

__device__ __forceinline__ float b2f(unsigned short u) {
    return __uint_as_float(((unsigned)u) << 16);
}
__device__ __forceinline__ unsigned short f2b(float f) {   // RNE, finite only
    unsigned x = __float_as_uint(f);
    return (unsigned short)((x + 0x7FFFu + ((x >> 16) & 1u)) >> 16);
}
__device__ __forceinline__ void split4(float4 x, unsigned short* h, unsigned short* l) {
    const float* xf = (const float*)&x;
    #pragma unroll
    for (int i = 0; i < 4; ++i) {
        h[i] = f2b(xf[i]);
        l[i] = f2b(xf[i] - b2f(h[i]));
    }
}
__device__ __forceinline__ uint2 pack4(const unsigned short* s) {
    uint2 w;
    w.x = s[0] | ((unsigned)s[1] << 16);
    w.y = s[2] | ((unsigned)s[3] << 16);
    return w;
}
// 8 f32 (scaled by cs) -> hi/lo bf16x8. Same RNE formula as the r7/r8 bc path.
__device__ __forceinline__ void split8s(float4 x0, float4 x1, float cs,
                                        bf16x8& hv, bf16x8& lv) {
    float xf[8] = {x0.x, x0.y, x0.z, x0.w, x1.x, x1.y, x1.z, x1.w};
    unsigned short h[8], l[8];
    #pragma unroll
    for (int i = 0; i < 8; ++i) {
        float v = cs * xf[i];
        h[i] = f2b(v);
        l[i] = f2b(v - b2f(h[i]));
    }
    uint4 hh, ll;
    hh.x = h[0] | ((unsigned)h[1] << 16); hh.y = h[2] | ((unsigned)h[3] << 16);
    hh.z = h[4] | ((unsigned)h[5] << 16); hh.w = h[6] | ((unsigned)h[7] << 16);
    ll.x = l[0] | ((unsigned)l[1] << 16); ll.y = l[2] | ((unsigned)l[3] << 16);
    ll.z = l[4] | ((unsigned)l[5] << 16); ll.w = l[6] | ((unsigned)l[7] << 16);
    hv = __builtin_bit_cast(bf16x8, hh);
    lv = __builtin_bit_cast(bf16x8, ll);
}

// Two-level grid barrier (r12 proven): sub[8]@128B apart -> root -> gen.
__device__ void gbar(unsigned* bar) {
    __syncthreads();
    if (threadIdx.x == 0) {
        unsigned* sub  = bar + 32 * (blockIdx.x & 7);
        unsigned* root = bar + 288;
        unsigned* gen  = bar + 320;
        unsigned g = __hip_atomic_load(gen, __ATOMIC_RELAXED, __HIP_MEMORY_SCOPE_AGENT);
        unsigned a = __hip_atomic_fetch_add(sub, 1u, __ATOMIC_ACQ_REL, __HIP_MEMORY_SCOPE_AGENT);
        if (a == (NBLK / 8) - 1) {
            __hip_atomic_store(sub, 0u, __ATOMIC_RELAXED, __HIP_MEMORY_SCOPE_AGENT);
            unsigned b = __hip_atomic_fetch_add(root, 1u, __ATOMIC_ACQ_REL, __HIP_MEMORY_SCOPE_AGENT);
            if (b == 7) {
                __hip_atomic_store(root, 0u, __ATOMIC_RELAXED, __HIP_MEMORY_SCOPE_AGENT);
                __hip_atomic_store(gen, g + 1u, __ATOMIC_RELEASE, __HIP_MEMORY_SCOPE_AGENT);
            }
        }
        while (__hip_atomic_load(gen, __ATOMIC_RELAXED, __HIP_MEMORY_SCOPE_AGENT) == g)
            __builtin_amdgcn_s_sleep(8);
        (void)__hip_atomic_load(gen, __ATOMIC_ACQUIRE, __HIP_MEMORY_SCOPE_AGENT);
    }
    __syncthreads();
}

// ---- sgemm + squash. Fragment maps proven r7-r12. mode 0: raw-P split +
// raw-W split, uniform c=0.1 post-MFMA. mode 1/2: Ph/Pl planes + c*W
// in-register (mode 2 = last, writes outb).
__device__ void sgemm_phase(
    const float4* __restrict__ P4,
    const uint4* __restrict__ Ah, const uint4* __restrict__ Al,
    const float4* __restrict__ W4, const float* __restrict__ Cc,
    uint2* __restrict__ vth, uint2* __restrict__ vtl,
    float* __restrict__ outb, int mode, float* comb)
{
    const int tid = threadIdx.x;
    const int wave = tid >> 6, lane = tid & 63;
    const int lm = lane & 15, q = lane >> 4;
    const int c = blockIdx.x / 16, b0 = (blockIdx.x % 16) * 16;

    const uint4* Ahp = Ah + (size_t)(b0 + lm) * 1152 + q;
    const uint4* Alp = Al + (size_t)(b0 + lm) * 1152 + q;
    const float4* Pp = P4 + (size_t)(b0 + lm) * 2304 + q * 2;
    const float4* Wp = W4 + ((size_t)q * 10 + c) * 32 + lm * 2;
    const float* Cp = Cc + q * 10 + c;

    v4f acc = {0.f, 0.f, 0.f, 0.f};
    const int kk0 = wave * 36;
    for (int kk = kk0; kk < kk0 + 36; ++kk) {
        bf16x8 ah, al, bh, bl;
        if (mode == 0) {
            float4 a0 = Pp[(size_t)kk * 8];
            float4 a1 = Pp[(size_t)kk * 8 + 1];
            split8s(a0, a1, 1.0f, ah, al);
        } else {
            ah = __builtin_bit_cast(bf16x8, Ahp[(size_t)kk * 4]);
            al = __builtin_bit_cast(bf16x8, Alp[(size_t)kk * 4]);
        }
        float4 w0 = Wp[(size_t)kk * 1280];      // W row r=kk*4+q, d=lm
        float4 w1 = Wp[(size_t)kk * 1280 + 1];
        const float cs = (mode == 0) ? 1.0f : Cp[kk * 40];
        split8s(w0, w1, cs, bh, bl);
        acc = __builtin_amdgcn_mfma_f32_16x16x32_bf16(ah, bh, acc, 0, 0, 0);
        acc = __builtin_amdgcn_mfma_f32_16x16x32_bf16(ah, bl, acc, 0, 0, 0);
        acc = __builtin_amdgcn_mfma_f32_16x16x32_bf16(al, bh, acc, 0, 0, 0);
    }
    #pragma unroll
    for (int r = 0; r < 4; ++r) comb[(wave * 64 + lane) * 4 + r] = acc[r];
    __syncthreads();
    if (wave == 0) {
        float s[4], sq[4];
        #pragma unroll
        for (int r = 0; r < 4; ++r) {
            s[r] = 0.f;
            #pragma unroll
            for (int w = 0; w < 8; ++w) s[r] += comb[(w * 64 + lane) * 4 + r];
            if (mode == 0) s[r] *= 0.1f;
            sq[r] = s[r] * s[r];
        }
        #pragma unroll
        for (int m = 1; m < 16; m <<= 1) {
            #pragma unroll
            for (int r = 0; r < 4; ++r) sq[r] += __shfl_xor(sq[r], m);
        }
        float v[4];
        #pragma unroll
        for (int r = 0; r < 4; ++r) {
            const float n = sq[r];
            v[r] = s[r] * sqrtf(n) / (1.0f + n);
        }
        if (mode != 2) {
            unsigned short h[4], l[4];
            #pragma unroll
            for (int r = 0; r < 4; ++r) {
                h[r] = f2b(v[r]);
                l[r] = f2b(v[r] - b2f(h[r]));
            }
            const int o = (c * 16 + lm) * 64 + (b0 >> 2) + q;   // uint2 units
            vth[o] = pack4(h);
            vtl[o] = pack4(l);
        } else {
            #pragma unroll
            for (int r = 0; r < 4; ++r)
                outb[((b0 + q * 4 + r) * 10 + c) * 16 + lm] = v[r];
        }
    }
}

// ---- tgemm + fused reduce/logits/softmax; emits c_coef (46KB) only.
__device__ void tr_phase(
    const uint4* __restrict__ vth, const uint4* __restrict__ vtl,
    const uint4* __restrict__ Pth, const uint4* __restrict__ Ptl,
    const float* __restrict__ Wf, float* __restrict__ c_coef, float* blog)
{
    const int tid = threadIdx.x;
    const int wave = tid >> 6, lane = tid & 63;
    const int lm = lane & 15, q = lane >> 4;
    const int t = wave * NBLK + blockIdx.x;
    if (t >= 576) return;
    const int n0 = t * 16;

    v4f acc[10];
    #pragma unroll
    for (int mt = 0; mt < 10; ++mt) acc[mt] = (v4f){0.f, 0.f, 0.f, 0.f};
    #pragma unroll
    for (int kk = 0; kk < 8; ++kk) {
        bf16x8 ph = __builtin_bit_cast(bf16x8, Pth[(size_t)(n0 + lm) * 32 + kk * 4 + q]);
        bf16x8 pl = __builtin_bit_cast(bf16x8, Ptl[(size_t)(n0 + lm) * 32 + kk * 4 + q]);
        #pragma unroll
        for (int mt = 0; mt < 10; ++mt) {
            bf16x8 vh = __builtin_bit_cast(bf16x8, vth[(size_t)(mt * 16 + lm) * 32 + kk * 4 + q]);
            bf16x8 vl = __builtin_bit_cast(bf16x8, vtl[(size_t)(mt * 16 + lm) * 32 + kk * 4 + q]);
            acc[mt] = __builtin_amdgcn_mfma_f32_16x16x32_bf16(vh, ph, acc[mt], 0, 0, 0);
            acc[mt] = __builtin_amdgcn_mfma_f32_16x16x32_bf16(vh, pl, acc[mt], 0, 0, 0);
            acc[mt] = __builtin_amdgcn_mfma_f32_16x16x32_bf16(vl, ph, acc[mt], 0, 0, 0);
        }
    }
    const int r = (n0 >> 3) + (lm >> 3);
    const int i = lm & 7;
    float a[10];
    #pragma unroll
    for (int c = 0; c < 10; ++c) {
        const float* wr = Wf + ((size_t)r * 10 + c) * 128 + i;
        float p = 0.f;
        #pragma unroll
        for (int rr = 0; rr < 4; ++rr)
            p = fmaf(wr[(q * 4 + rr) * 8], acc[c][rr], p);   // d = q*4+rr
        a[c] = p;
    }
    const int masks[5] = {16, 32, 1, 2, 4};
    #pragma unroll
    for (int m = 0; m < 5; ++m) {
        #pragma unroll
        for (int c = 0; c < 10; ++c) a[c] += __shfl_xor(a[c], masks[m]);
    }
    float mx = -1e30f;
    #pragma unroll
    for (int c = 0; c < 10; ++c) {
        blog[c] += a[c] * (1.0f / 256.0f);
        mx = fmaxf(mx, blog[c]);
    }
    float cl[10], den = 0.f;
    #pragma unroll
    for (int c = 0; c < 10; ++c) { cl[c] = __expf(blog[c] - mx); den += cl[c]; }
    const float inv = 1.0f / den;
    const int li = i * 4 + q;             // lane id within the 32-lane r-group
    #pragma unroll
    for (int c = 0; c < 10; ++c)
        if (li == c) c_coef[r * 10 + c] = cl[c] * inv;
}

__global__ __launch_bounds__(512, 2) void mega_kernel(
    const float4* __restrict__ P4, const float4* __restrict__ W4,
    uint2* __restrict__ Ph, uint2* __restrict__ Pl,
    uint4* __restrict__ Pth, uint4* __restrict__ Ptl,
    float* __restrict__ c_coef,
    uint2* __restrict__ vth, uint2* __restrict__ vtl,
    float* __restrict__ outb, unsigned* __restrict__ bar)
{
    __shared__ union {
        unsigned short sp[2][2][64 * 72];   // [halfblock][H/L] 36864 B
        float comb[8 * 64 * 4];             // 8192 B
    } sh;
    const int tid = threadIdx.x;
    const int bx = blockIdx.x;

    // ---- phase A part 1: P split + transpose (r9-proven tile maps) ----
    {
        const int half = tid >> 8, t2 = tid & 255;
        unsigned short* ldsH = sh.sp[half][0];
        unsigned short* ldsL = sh.sp[half][1];
        const int hb = bx * 2 + half;       // 0..319
        for (int t = hb; t < 640; t += 320) {
            const bool act = t < 576;
            const int b0 = (t & 3) * 64, k0 = (t >> 2) * 64;
            if (act) {
                #pragma unroll
                for (int j = 0; j < 4; ++j) {
                    int idx = t2 + j * 256;
                    int row = idx >> 4, col4 = idx & 15;
                    int g = (b0 + row) * 2304 + (k0 >> 2) + col4;
                    unsigned short h[4], l[4];
                    split4(P4[g], h, l);
                    Ph[g] = pack4(h);
                    Pl[g] = pack4(l);
                    #pragma unroll
                    for (int i2 = 0; i2 < 4; ++i2) {
                        ldsH[(col4 * 4 + i2) * 72 + row] = h[i2];
                        ldsL[(col4 * 4 + i2) * 72 + row] = l[i2];
                    }
                }
            }
            __syncthreads();
            if (act) {
                #pragma unroll
                for (int j = 0; j < 2; ++j) {
                    int idx = t2 + j * 256;
                    int krow = idx >> 3, bcol = idx & 7;
                    unsigned short h[8], l[8];
                    #pragma unroll
                    for (int i2 = 0; i2 < 8; ++i2) {
                        h[i2] = ldsH[krow * 72 + bcol * 8 + i2];
                        l[i2] = ldsL[krow * 72 + bcol * 8 + i2];
                    }
                    uint4 wh, wl;
                    wh.x = h[0] | ((unsigned)h[1] << 16); wh.y = h[2] | ((unsigned)h[3] << 16);
                    wh.z = h[4] | ((unsigned)h[5] << 16); wh.w = h[6] | ((unsigned)h[7] << 16);
                    wl.x = l[0] | ((unsigned)l[1] << 16); wl.y = l[2] | ((unsigned)l[3] << 16);
                    wl.z = l[4] | ((unsigned)l[5] << 16); wl.w = l[6] | ((unsigned)l[7] << 16);
                    Pth[(size_t)(k0 + krow) * 32 + (b0 >> 3) + bcol] = wh;
                    Ptl[(size_t)(k0 + krow) * 32 + (b0 >> 3) + bcol] = wl;
                }
            }
            __syncthreads();
        }
    }

    float blog[10];
    #pragma unroll
    for (int c = 0; c < 10; ++c) blog[c] = 0.f;
    const float* Wf = (const float*)W4;
    const uint4* Ah = (const uint4*)Ph;
    const uint4* Al = (const uint4*)Pl;

    // ---- phase A part 2: sgemm0 from raw P/W (in-register split), uniform
    sgemm_phase(P4, Ah, Al, W4, c_coef, vth, vtl, outb, 0, sh.comb);
    gbar(bar);
    tr_phase((const uint4*)vth, (const uint4*)vtl, Pth, Ptl, Wf, c_coef, blog);
    gbar(bar);
    sgemm_phase(P4, Ah, Al, W4, c_coef, vth, vtl, outb, 1, sh.comb);
    gbar(bar);
    tr_phase((const uint4*)vth, (const uint4*)vtl, Pth, Ptl, Wf, c_coef, blog);
    gbar(bar);
    sgemm_phase(P4, Ah, Al, W4, c_coef, vth, vtl, outb, 2, sh.comb);
}

extern "C" void kernel_launch(void* const* d_in, const int* in_sizes, int n_in,
                              void* d_out, int out_size, void* d_ws, size_t ws_size,
                              hipStream_t stream)
{
    const float4* P4 = (const float4*)d_in[0];
    const float4* W4 = (const float4*)d_in[1];
    char* wsb = (char*)d_ws;
    uint2* vth = (uint2*)(wsb + 131072);            // 81920 B
    uint2* vtl = (uint2*)(wsb + 262144);            // 81920 B
    uint2* Ph  = (uint2*)(wsb + 393216);            // 4718592 B
    uint2* Pl  = (uint2*)(wsb + 5242880);           // 4718592 B
    uint4* Pth = (uint4*)(wsb + 10485760);          // 4718592 B
    uint4* Ptl = (uint4*)(wsb + 15728640);          // 4718592 B
    float* c_coef = (float*)(wsb + 20971520);       // 46080 B
    unsigned* bar = (unsigned*)(wsb + 36700160);
    float* outb = (float*)d_out;

    (void)hipMemsetAsync(bar, 0, 2048, stream);  // zero sub/root/gen counters
    mega_kernel<<<NBLK, 512, 0, stream>>>(P4, W4, Ph, Pl, Pth, Ptl, c_coef,
                                          vth, vtl, outb, bar);
}